// Round 2
// baseline (561.482 us; speedup 1.0000x reference)
//
#include <hip/hip_runtime.h>
#include <hip/hip_bf16.h>

#define THRESHOLD 0.4f
#define HM_H 128
#define HM_W 128

// One thread per (b,k): load coord pair (u,v), flip to (v,u), bounds-check,
// gather heatmaps[b,k,v_clipped,u_clipped], emit (in_bounds && val>thr) as int 0/1.
__global__ __launch_bounds__(256) void VisibilityHeatmap_41841571398294_kernel(
    const int2* __restrict__ coords,      // [B*K] pairs, .x = u, .y = v (UV order)
    const float* __restrict__ heatmaps,   // [B*K, H, W]
    int* __restrict__ out,                // [B*K] int32 bool mask
    int n)                                 // n = B*K
{
    int i = blockIdx.x * blockDim.x + threadIdx.x;
    if (i >= n) return;

    int2 c = coords[i];          // coalesced 8B/lane
    int u = c.x;
    int v = c.y;                 // flip(-1): (u,v) -> (v,u)

    bool in_bounds = (v > -1) & (u > -1) & (v < HM_H) & (u < HM_W);

    int vc = min(max(v, 0), HM_H - 1);
    int uc = min(max(u, 0), HM_W - 1);

    // Gather: scattered within each (b,k) 64KB plane; L2/L3 absorbs.
    float val = heatmaps[(size_t)i * (HM_H * HM_W) + vc * HM_W + uc];

    out[i] = (in_bounds && (val > THRESHOLD)) ? 1 : 0;
}

extern "C" void kernel_launch(void* const* d_in, const int* in_sizes, int n_in,
                              void* d_out, int out_size, void* d_ws, size_t ws_size,
                              hipStream_t stream) {
    const int2*  coords   = (const int2*)d_in[0];    // int32 [B,K,2] -> int2 pairs
    const float* heatmaps = (const float*)d_in[1];   // float32 [B,K,H,W]
    int*         out      = (int*)d_out;             // bool mask stored as int32

    int n = in_sizes[0] / 2;  // B*K pairs (16384 ints -> 8192 pairs)

    int block = 256;
    int grid = (n + block - 1) / block;  // 32 blocks
    VisibilityHeatmap_41841571398294_kernel<<<grid, block, 0, stream>>>(
        coords, heatmaps, out, n);
}